// Round 14
// baseline (268.299 us; speedup 1.0000x reference)
//
#include <hip/hip_runtime.h>

#define NNODES 50000
#define NEDGES 800000
#define CHUNK 3125          // edges per CSR block (256 blocks * 3125 = 800000)
#define SENT 0x7FFFFFFF

typedef __attribute__((ext_vector_type(8))) short short8;
typedef __attribute__((ext_vector_type(4))) float floatx4;
typedef __attribute__((ext_vector_type(8))) _Float16 f16x8;

// async global->LDS, 16B per lane (global_load_lds_dwordx4).
// LDS dest MUST be wave-uniform base + lane*16.
__device__ __forceinline__ void async16(const void* g, void* l) {
    __builtin_amdgcn_global_load_lds(
        (const __attribute__((address_space(1))) unsigned int*)g,
        (__attribute__((address_space(3))) unsigned int*)l, 16, 0, 0);
}

__device__ __forceinline__ void split_bf16(float v, short& hi, short& lo) {
    unsigned u = __float_as_uint(v);
    unsigned hu = u & 0xffff0000u;
    hi = (short)(hu >> 16);
    float r = v - __uint_as_float(hu);
    lo = (short)(__float_as_uint(r) >> 16);
}

// ------ prep: weight transpose/split + coarse histogram ------------------

#define PREP_WBLK 224
#define PREP_TOT  (PREP_WBLK + 256)

__global__ __launch_bounds__(256) void k_prep(
    const float* __restrict__ W0, short* __restrict__ W0h, short* __restrict__ W0l,
    const float* __restrict__ W1, short* __restrict__ W1h, short* __restrict__ W1l,
    const float* __restrict__ W2, short* __restrict__ W2h, short* __restrict__ W2l,
    const int* __restrict__ dst, int* __restrict__ hist2d) {
    int b = blockIdx.x, t = threadIdx.x;
    if (b < PREP_WBLK) {
        int id = b * 256 + t;
        const float* W; short *Wh, *Wl; int K, F;
        if (id < 32768) { W = W0; Wh = W0h; Wl = W0l; K = 256; F = 128; }
        else if (id < 49152) { id -= 32768; W = W1; Wh = W1h; Wl = W1l; K = 128; F = 128; }
        else if (id < 57344) { id -= 49152; W = W2; Wh = W2h; Wl = W2l; K = 128; F = 64; }
        else return;
        int f = id / K, k = id - f * K;
        short h, l;
        split_bf16(W[(size_t)k * F + f], h, l);
        Wh[id] = h;
        Wl[id] = l;
    } else {
        // per-block coarse histogram of dst>>8 (no global atomics)
        __shared__ int h[256];
        int bb = b - PREP_WBLK;
        h[t] = 0;
        __syncthreads();
        int e0 = bb * CHUNK;
#pragma unroll
        for (int k = 0; k < 13; k++) {
            int o = k * 256 + t;
            if (o < CHUNK) atomicAdd(&h[dst[e0 + o] >> 8], 1);
        }
        __syncthreads();
        hist2d[bb * 256 + t] = h[t];
    }
}

// P2 (self-scanning): deterministic coarse scatter, LDS cursors only.
__global__ __launch_bounds__(256) void k_p2(const int* __restrict__ src,
                                            const int* __restrict__ dst,
                                            const int* __restrict__ hist2d,
                                            unsigned* __restrict__ buck) {
    __shared__ int ex[256], cur[256];
    int t = threadIdx.x, b = blockIdx.x;
    int tot = 0, pre = 0;
    for (int bb = 0; bb < 256; bb++) {
        int v = hist2d[bb * 256 + t];
        tot += v;
        pre += (bb < b) ? v : 0;
    }
    ex[t] = tot;
    __syncthreads();
    for (int o = 1; o < 256; o <<= 1) {
        int xx = (t >= o) ? ex[t - o] : 0;
        __syncthreads();
        ex[t] += xx;
        __syncthreads();
    }
    cur[t] = (ex[t] - tot) + pre;
    __syncthreads();
    int e0 = b * CHUNK;
#pragma unroll
    for (int k = 0; k < 13; k++) {
        int o = k * 256 + t;
        if (o < CHUNK) {
            int s = src[e0 + o], d = dst[e0 + o];
            int p = atomicAdd(&cur[d >> 8], 1);   // LDS atomic only
            buck[p] = (unsigned)s | ((unsigned)(d & 255) << 16);
        }
    }
}

// P3 (self-scanning): finalize coarse bin b -> rowptr/dinv/ssrc, plus a
// per-block degree counting-sort emitting perm[] (degree-uniform node
// groups for the agg — removes exec-mask divergence waste).
__global__ __launch_bounds__(256) void k_p3(const unsigned* __restrict__ buck,
                                            const int* __restrict__ hist2d,
                                            int* __restrict__ rowptr,
                                            float* __restrict__ dinv,
                                            int* __restrict__ ssrc,
                                            int* __restrict__ perm) {
    __shared__ int ex[256], cur[256], h[256], sS0[1], sS[1];
    int t = threadIdx.x, b = blockIdx.x;
    int tot = 0;
    for (int bb = 0; bb < 256; bb++) tot += hist2d[bb * 256 + t];
    ex[t] = tot;
    __syncthreads();
    for (int o = 1; o < 256; o <<= 1) {
        int xx = (t >= o) ? ex[t - o] : 0;
        __syncthreads();
        ex[t] += xx;
        __syncthreads();
    }
    if (t == b) { sS0[0] = ex[t] - tot; sS[0] = tot; }
    h[t] = 0;
    __syncthreads();
    int s0 = sS0[0], S = sS[0];
    for (int i = t; i < S; i += 256)
        atomicAdd(&h[(buck[s0 + i] >> 16) & 255], 1);
    __syncthreads();
    int v = h[t];
    ex[t] = v;
    __syncthreads();
    for (int o = 1; o < 256; o <<= 1) {
        int xx = (t >= o) ? ex[t - o] : 0;
        __syncthreads();
        ex[t] += xx;
        __syncthreads();
    }
    int excl = ex[t] - v;
    int n = b * 256 + t;
    bool valid = (n < NNODES);
    if (valid) {
        rowptr[n] = s0 + excl;
        dinv[n] = rsqrtf((float)v + 1.0f);
    }
    if (b == 0 && t == 0) rowptr[NNODES] = NEDGES;
    cur[t] = excl;
    __syncthreads();
    for (int i = t; i < S; i += 256) {
        unsigned pk = buck[s0 + i];
        int dl = (pk >> 16) & 255;
        int p = atomicAdd(&cur[dl], 1);
        ssrc[s0 + p] = (int)(pk & 0xFFFFu);
    }

    // ---- degree counting-sort -> perm (block-local; reuse LDS) ----
    __syncthreads();
    int bin = valid ? (v < 64 ? v : 63) : 63;
    h[t] = 0;
    __syncthreads();
    int myIdx = atomicAdd(&h[bin], 1);
    __syncthreads();
    int hv = h[t];
    ex[t] = hv;
    __syncthreads();
    for (int o = 1; o < 256; o <<= 1) {
        int xx = (t >= o) ? ex[t - o] : 0;
        __syncthreads();
        ex[t] += xx;
        __syncthreads();
    }
    __syncthreads();
    // exclusive prefix of my bin (broadcast via LDS read)
    int base = ex[bin] - h[bin];
    perm[b * 256 + base + myIdx] = valid ? n : SENT;
}

// ------ gemm0: g16 = fp16((x @ W0) * dinv[row]) --------------------------
// Direct fp32 x read + in-register split, XOR-swizzled LDS-A (proven R9).

__global__ __launch_bounds__(256) void k_gemm0(
    const float* __restrict__ x, const short* __restrict__ Bh,
    const short* __restrict__ Bl, const float* __restrict__ dinv,
    _Float16* __restrict__ g16) {
    __shared__ __align__(16) short sAh[64 * 64], sAl[64 * 64];
    __shared__ __align__(16) short sBh[128 * 64], sBl[128 * 64];
    const int t = threadIdx.x, lane = t & 63, w = t >> 6;
    const int row0 = blockIdx.x * 64;
    const int lr = lane >> 3, lz = lane & 7;
    const int swz = (lz ^ lr) * 8;
    const int fr = lane & 15, fq = lane >> 4;
    floatx4 acc[8] = {};
    const int ar = t >> 2, ac = t & 3;
    int garow = row0 + ar;
    if (garow >= NNODES) garow = NNODES - 1;
    const float* xrow = x + (size_t)garow * 256 + ac * 16;

    for (int k0 = 0; k0 < 256; k0 += 64) {
        const float4* xp = (const float4*)(xrow + k0);
        float4 f0 = xp[0], f1 = xp[1], f2 = xp[2], f3 = xp[3];
        float va[16] = {f0.x, f0.y, f0.z, f0.w, f1.x, f1.y, f1.z, f1.w,
                        f2.x, f2.y, f2.z, f2.w, f3.x, f3.y, f3.z, f3.w};
        short8 h0, h1, l0, l1;
#pragma unroll
        for (int j = 0; j < 8; j++) {
            short h, l;
            split_bf16(va[j], h, l);     h0[j] = h; l0[j] = l;
            split_bf16(va[8 + j], h, l); h1[j] = h; l1[j] = l;
        }
        int c0 = ac * 2;
        *(short8*)&sAh[ar * 64 + ((c0 ^ (ar & 7)) * 8)] = h0;
        *(short8*)&sAh[ar * 64 + (((c0 + 1) ^ (ar & 7)) * 8)] = h1;
        *(short8*)&sAl[ar * 64 + ((c0 ^ (ar & 7)) * 8)] = l0;
        *(short8*)&sAl[ar * 64 + (((c0 + 1) ^ (ar & 7)) * 8)] = l1;
#pragma unroll
        for (int jj = 0; jj < 4; jj++) {
            int j = w * 4 + jj;
            size_t go = (size_t)(j * 8 + lr) * 256 + k0 + swz;
            async16(&Bh[go], &sBh[j * 512 + lane * 8]);
            async16(&Bl[go], &sBl[j * 512 + lane * 8]);
        }
        __syncthreads();
#pragma unroll
        for (int ks = 0; ks < 2; ks++) {
            int R = w * 16 + fr;
            int ca = ((ks * 4 + fq) ^ (R & 7)) * 8;
            short8 ah = *(const short8*)&sAh[R * 64 + ca];
            short8 al = *(const short8*)&sAl[R * 64 + ca];
#pragma unroll
            for (int nt = 0; nt < 8; nt++) {
                int n = nt * 16 + fr;
                int cb = ((ks * 4 + fq) ^ (n & 7)) * 8;
                short8 bh = *(const short8*)&sBh[n * 64 + cb];
                short8 bl = *(const short8*)&sBl[n * 64 + cb];
                acc[nt] = __builtin_amdgcn_mfma_f32_16x16x32_bf16(ah, bh, acc[nt], 0, 0, 0);
                acc[nt] = __builtin_amdgcn_mfma_f32_16x16x32_bf16(ah, bl, acc[nt], 0, 0, 0);
                acc[nt] = __builtin_amdgcn_mfma_f32_16x16x32_bf16(al, bh, acc[nt], 0, 0, 0);
            }
        }
        __syncthreads();
    }
#pragma unroll
    for (int rr = 0; rr < 4; rr++) {
        int gw = row0 + w * 16 + fq * 4 + rr;
        if (gw < NNODES) {
            float dv = dinv[gw];
#pragma unroll
            for (int nt = 0; nt < 8; nt++)
                g16[(size_t)gw * 128 + nt * 16 + fr] =
                    (_Float16)(acc[nt][rr] * dv);
        }
    }
}

// ------ gemm (layers 1/2): g16 = fp16((A @ W) * dinv), proven R8 ---------

template <int BN>
__global__ __launch_bounds__(256) void k_gemm2(
    const short* __restrict__ Ah, const short* __restrict__ Al,
    const short* __restrict__ Bh, const short* __restrict__ Bl,
    const float* __restrict__ dinv, _Float16* __restrict__ g16, int K) {
    constexpr int BM = 64, BK = 64;
    constexpr int NT = BN / 16;
    __shared__ __align__(16) short sAh[BM * BK], sAl[BM * BK];
    __shared__ __align__(16) short sBh[BN * BK], sBl[BN * BK];

    const int tid = threadIdx.x, lane = tid & 63, w = tid >> 6;
    const int row0 = blockIdx.x * BM;
    const int lr = lane >> 3;
    const int lz = lane & 7;
    const int swz = (lz ^ lr) * 8;
    const int fr = lane & 15, fq = lane >> 4;

    floatx4 acc[NT] = {};

    for (int k0 = 0; k0 < K; k0 += BK) {
#pragma unroll
        for (int jj = 0; jj < 2; jj++) {
            int j = w * 2 + jj;
            int grow = row0 + j * 8 + lr;
            if (grow >= NNODES) grow = NNODES - 1;
            size_t go = (size_t)grow * K + k0 + swz;
            async16(&Ah[go], &sAh[j * 8 * BK + lane * 8]);
            async16(&Al[go], &sAl[j * 8 * BK + lane * 8]);
        }
#pragma unroll
        for (int jj = 0; jj < BN / 32; jj++) {
            int j = w * (BN / 32) + jj;
            size_t go = (size_t)(j * 8 + lr) * K + k0 + swz;
            async16(&Bh[go], &sBh[j * 8 * BK + lane * 8]);
            async16(&Bl[go], &sBl[j * 8 * BK + lane * 8]);
        }
        __syncthreads();

#pragma unroll
        for (int ks = 0; ks < 2; ks++) {
            int R = w * 16 + fr;
            int ca = ((ks * 4 + fq) ^ (R & 7)) * 8;
            short8 ah = *(const short8*)&sAh[R * BK + ca];
            short8 al = *(const short8*)&sAl[R * BK + ca];
#pragma unroll
            for (int nt = 0; nt < NT; nt++) {
                int n = nt * 16 + fr;
                int cb = ((ks * 4 + fq) ^ (n & 7)) * 8;
                short8 bh = *(const short8*)&sBh[n * BK + cb];
                short8 bl = *(const short8*)&sBl[n * BK + cb];
                acc[nt] = __builtin_amdgcn_mfma_f32_16x16x32_bf16(ah, bh, acc[nt], 0, 0, 0);
                acc[nt] = __builtin_amdgcn_mfma_f32_16x16x32_bf16(ah, bl, acc[nt], 0, 0, 0);
                acc[nt] = __builtin_amdgcn_mfma_f32_16x16x32_bf16(al, bh, acc[nt], 0, 0, 0);
            }
        }
        __syncthreads();
    }

#pragma unroll
    for (int rr = 0; rr < 4; rr++) {
        int grow = row0 + w * 16 + fq * 4 + rr;
        if (grow < NNODES) {
            float dv = dinv[grow];
#pragma unroll
            for (int nt = 0; nt < NT; nt++)
                g16[(size_t)grow * BN + nt * 16 + fr] =
                    (_Float16)(acc[nt][rr] * dv);
        }
    }
}

// ------ Aggregation: degree-sorted nodes (perm) + LDS edge broadcast -----
// F8 threads per node; node = perm[...] so co-scheduled nodes have nearly
// equal degree (no exec-mask waste). Edge list broadcast via LDS.

template <int F>
__global__ __launch_bounds__(256) void k_agg(const _Float16* __restrict__ g,
                                             const int* __restrict__ ssrc,
                                             const int* __restrict__ rowptr,
                                             const int* __restrict__ perm,
                                             const float* __restrict__ dinv,
                                             const float* __restrict__ bias,
                                             float* __restrict__ outf,
                                             short* __restrict__ oh,
                                             short* __restrict__ ol,
                                             int relu, int writebf) {
    constexpr int F8 = F / 8;          // threads per node (16 or 8)
    constexpr int NPB = 256 / F8;      // nodes per block (16 or 32)
    __shared__ int sED[NPB][64];
    int t = threadIdx.x;
    int ln = t / F8;
    int c8 = t - ln * F8;
    int n = perm[blockIdx.x * NPB + ln];
    bool valid = (n < NNODES);
    int nc = valid ? n : NNODES - 1;

    int e0 = rowptr[nc], e1 = rowptr[nc + 1];
    int deg = e1 - e0;
    int cnt = deg < 64 ? deg : 64;
    for (int i = c8; i < cnt; i += F8) sED[ln][i] = ssrc[e0 + i];
    __syncthreads();

    const f16x8* gp = (const f16x8*)g;
    f16x8 sv = gp[(size_t)nc * F8 + c8];       // self term
    float a0[8], a1[8], a2[8], a3[8];
#pragma unroll
    for (int j = 0; j < 8; j++) {
        a0[j] = (float)sv[j];
        a1[j] = 0.f; a2[j] = 0.f; a3[j] = 0.f;
    }
    int i = 0;
    for (; i + 4 <= cnt; i += 4) {
        int s0 = sED[ln][i], s1 = sED[ln][i + 1];
        int s2 = sED[ln][i + 2], s3 = sED[ln][i + 3];
        f16x8 v0 = gp[(size_t)s0 * F8 + c8];
        f16x8 v1 = gp[(size_t)s1 * F8 + c8];
        f16x8 v2 = gp[(size_t)s2 * F8 + c8];
        f16x8 v3 = gp[(size_t)s3 * F8 + c8];
#pragma unroll
        for (int j = 0; j < 8; j++) {
            a0[j] += (float)v0[j];
            a1[j] += (float)v1[j];
            a2[j] += (float)v2[j];
            a3[j] += (float)v3[j];
        }
    }
    for (; i < cnt; i++) {
        int s = sED[ln][i];
        f16x8 v = gp[(size_t)s * F8 + c8];
#pragma unroll
        for (int j = 0; j < 8; j++) a0[j] += (float)v[j];
    }
    // rare overflow (deg > 64): direct from global
    for (int e = e0 + 64; e < e1; e++) {
        int s = ssrc[e];
        f16x8 v = gp[(size_t)s * F8 + c8];
#pragma unroll
        for (int j = 0; j < 8; j++) a0[j] += (float)v[j];
    }

    float dv = dinv[nc];
    float o[8];
#pragma unroll
    for (int j = 0; j < 8; j++) {
        float s = (a0[j] + a1[j]) + (a2[j] + a3[j]);
        o[j] = s * dv + bias[c8 * 8 + j];
        if (relu) o[j] = fmaxf(o[j], 0.f);
    }
    if (!valid) return;
    if (writebf) {
        short8 h8, l8;
#pragma unroll
        for (int j = 0; j < 8; j++) {
            short h, l;
            split_bf16(o[j], h, l);
            h8[j] = h; l8[j] = l;
        }
        *(short8*)&oh[(size_t)n * F + c8 * 8] = h8;
        *(short8*)&ol[(size_t)n * F + c8 * 8] = l8;
    } else {
        *(float4*)&outf[(size_t)n * F + c8 * 8] =
            make_float4(o[0], o[1], o[2], o[3]);
        *(float4*)&outf[(size_t)n * F + c8 * 8 + 4] =
            make_float4(o[4], o[5], o[6], o[7]);
    }
}

// ---------------- launch ----------------

static inline size_t align256(size_t x) { return (x + 255) & ~(size_t)255; }

extern "C" void kernel_launch(void* const* d_in, const int* in_sizes, int n_in,
                              void* d_out, int out_size, void* d_ws, size_t ws_size,
                              hipStream_t stream) {
    const float* x  = (const float*)d_in[0];
    const int*   ei = (const int*)d_in[1];
    const float* W0 = (const float*)d_in[2];
    const float* b0 = (const float*)d_in[3];
    const float* W1 = (const float*)d_in[4];
    const float* b1 = (const float*)d_in[5];
    const float* W2 = (const float*)d_in[6];
    const float* b2 = (const float*)d_in[7];
    float* out = (float*)d_out;

    const int* src = ei;
    const int* dst = ei + NEDGES;

    char* w = (char*)d_ws;
    size_t off = 0;
    float* dinv    = (float*)(w + off); off = align256(off + NNODES * 4);
    int* rowptr    = (int*)(w + off);   off = align256(off + (NNODES + 1) * 4);
    int* perm      = (int*)(w + off);   off = align256(off + 65536 * 4);
    int* hist2d    = (int*)(w + off);   off = align256(off + 256 * 256 * 4);
    unsigned* buck = (unsigned*)(w + off); off = align256(off + (size_t)NEDGES * 4);
    int* ssrc      = (int*)(w + off);   off = align256(off + (size_t)NEDGES * 4);
    short* W0h     = (short*)(w + off); off = align256(off + 256 * 128 * 2);
    short* W0l     = (short*)(w + off); off = align256(off + 256 * 128 * 2);
    short* W1h     = (short*)(w + off); off = align256(off + 128 * 128 * 2);
    short* W1l     = (short*)(w + off); off = align256(off + 128 * 128 * 2);
    short* W2h     = (short*)(w + off); off = align256(off + 128 * 64 * 2);
    short* W2l     = (short*)(w + off); off = align256(off + 128 * 64 * 2);
    short* ph      = (short*)(w + off); off = align256(off + (size_t)NNODES * 128 * 2);
    short* pl      = (short*)(w + off); off = align256(off + (size_t)NNODES * 128 * 2);
    _Float16* g16  = (_Float16*)(w + off); off = align256(off + (size_t)NNODES * 128 * 2);

    const int MB = (NNODES + 63) / 64;            // 782
    const int PN = 196 * 256;                     // perm entries covering nodes
    const int AB128 = PN / 16;                    // 3136 (16 nodes/block)
    const int AB64  = PN / 32;                    // 1568 (32 nodes/block)

    // 1) prep: weights + coarse histogram
    k_prep<<<PREP_TOT, 256, 0, stream>>>(W0, W0h, W0l, W1, W1h, W1l,
                                         W2, W2h, W2l, dst, hist2d);
    // 2) coarse scatter
    k_p2<<<256, 256, 0, stream>>>(src, dst, hist2d, buck);
    // 3) finalize: rowptr/dinv/ssrc + degree-sorted perm
    k_p3<<<256, 256, 0, stream>>>(buck, hist2d, rowptr, dinv, ssrc, perm);

    // layer 0 (direct x)
    k_gemm0<<<MB, 256, 0, stream>>>(x, W0h, W0l, dinv, g16);
    k_agg<128><<<AB128, 256, 0, stream>>>(g16, ssrc, rowptr, perm, dinv, b0,
                                          (float*)nullptr, ph, pl, 1, 1);
    // layer 1
    k_gemm2<128><<<MB, 256, 0, stream>>>(ph, pl, W1h, W1l, dinv, g16, 128);
    k_agg<128><<<AB128, 256, 0, stream>>>(g16, ssrc, rowptr, perm, dinv, b1,
                                          (float*)nullptr, ph, pl, 1, 1);
    // layer 2
    k_gemm2<64><<<MB, 256, 0, stream>>>(ph, pl, W2h, W2l, dinv, g16, 128);
    k_agg<64><<<AB64, 256, 0, stream>>>(g16, ssrc, rowptr, perm, dinv, b2,
                                        out, (short*)nullptr, (short*)nullptr, 0, 0);
    (void)in_sizes; (void)n_in; (void)out_size; (void)ws_size;
}

// Round 15
// 256.774 us; speedup vs baseline: 1.0449x; 1.0449x over previous
//
#include <hip/hip_runtime.h>

#define NNODES 50000
#define NEDGES 800000
#define CHUNK 3125          // edges per CSR block (256 blocks * 3125 = 800000)

typedef __attribute__((ext_vector_type(8))) short short8;
typedef __attribute__((ext_vector_type(4))) float floatx4;
typedef __attribute__((ext_vector_type(8))) _Float16 f16x8;

// async global->LDS, 16B per lane (global_load_lds_dwordx4).
// LDS dest MUST be wave-uniform base + lane*16.
__device__ __forceinline__ void async16(const void* g, void* l) {
    __builtin_amdgcn_global_load_lds(
        (const __attribute__((address_space(1))) unsigned int*)g,
        (__attribute__((address_space(3))) unsigned int*)l, 16, 0, 0);
}

__device__ __forceinline__ void split_bf16(float v, short& hi, short& lo) {
    unsigned u = __float_as_uint(v);
    unsigned hu = u & 0xffff0000u;
    hi = (short)(hu >> 16);
    float r = v - __uint_as_float(hu);
    lo = (short)(__float_as_uint(r) >> 16);
}

// ------ prep: weight transpose/split + coarse histogram ------------------

#define PREP_WBLK 224
#define PREP_TOT  (PREP_WBLK + 256)

__global__ __launch_bounds__(256) void k_prep(
    const float* __restrict__ W0, short* __restrict__ W0h, short* __restrict__ W0l,
    const float* __restrict__ W1, short* __restrict__ W1h, short* __restrict__ W1l,
    const float* __restrict__ W2, short* __restrict__ W2h, short* __restrict__ W2l,
    const int* __restrict__ dst, int* __restrict__ hist2d) {
    int b = blockIdx.x, t = threadIdx.x;
    if (b < PREP_WBLK) {
        int id = b * 256 + t;
        const float* W; short *Wh, *Wl; int K, F;
        if (id < 32768) { W = W0; Wh = W0h; Wl = W0l; K = 256; F = 128; }
        else if (id < 49152) { id -= 32768; W = W1; Wh = W1h; Wl = W1l; K = 128; F = 128; }
        else if (id < 57344) { id -= 49152; W = W2; Wh = W2h; Wl = W2l; K = 128; F = 64; }
        else return;
        int f = id / K, k = id - f * K;
        short h, l;
        split_bf16(W[(size_t)k * F + f], h, l);
        Wh[id] = h;
        Wl[id] = l;
    } else {
        // per-block coarse histogram of dst>>8 (no global atomics)
        __shared__ int h[256];
        int bb = b - PREP_WBLK;
        h[t] = 0;
        __syncthreads();
        int e0 = bb * CHUNK;
#pragma unroll
        for (int k = 0; k < 13; k++) {
            int o = k * 256 + t;
            if (o < CHUNK) atomicAdd(&h[dst[e0 + o] >> 8], 1);
        }
        __syncthreads();
        hist2d[bb * 256 + t] = h[t];
    }
}

// P2 (self-scanning): deterministic coarse scatter, LDS cursors only.
__global__ __launch_bounds__(256) void k_p2(const int* __restrict__ src,
                                            const int* __restrict__ dst,
                                            const int* __restrict__ hist2d,
                                            unsigned* __restrict__ buck) {
    __shared__ int ex[256], cur[256];
    int t = threadIdx.x, b = blockIdx.x;
    int tot = 0, pre = 0;
    for (int bb = 0; bb < 256; bb++) {
        int v = hist2d[bb * 256 + t];
        tot += v;
        pre += (bb < b) ? v : 0;
    }
    ex[t] = tot;
    __syncthreads();
    for (int o = 1; o < 256; o <<= 1) {
        int xx = (t >= o) ? ex[t - o] : 0;
        __syncthreads();
        ex[t] += xx;
        __syncthreads();
    }
    cur[t] = (ex[t] - tot) + pre;
    __syncthreads();
    int e0 = b * CHUNK;
#pragma unroll
    for (int k = 0; k < 13; k++) {
        int o = k * 256 + t;
        if (o < CHUNK) {
            int s = src[e0 + o], d = dst[e0 + o];
            int p = atomicAdd(&cur[d >> 8], 1);   // LDS atomic only
            buck[p] = (unsigned)s | ((unsigned)(d & 255) << 16);
        }
    }
}

// P3 (self-scanning): finalize coarse bin b -> rowptr/dinv/ssrc.
__global__ __launch_bounds__(256) void k_p3(const unsigned* __restrict__ buck,
                                            const int* __restrict__ hist2d,
                                            int* __restrict__ rowptr,
                                            float* __restrict__ dinv,
                                            int* __restrict__ ssrc) {
    __shared__ int ex[256], cur[256], h[256], sS0[1], sS[1];
    int t = threadIdx.x, b = blockIdx.x;
    int tot = 0;
    for (int bb = 0; bb < 256; bb++) tot += hist2d[bb * 256 + t];
    ex[t] = tot;
    __syncthreads();
    for (int o = 1; o < 256; o <<= 1) {
        int xx = (t >= o) ? ex[t - o] : 0;
        __syncthreads();
        ex[t] += xx;
        __syncthreads();
    }
    if (t == b) { sS0[0] = ex[t] - tot; sS[0] = tot; }
    h[t] = 0;
    __syncthreads();
    int s0 = sS0[0], S = sS[0];
    for (int i = t; i < S; i += 256)
        atomicAdd(&h[(buck[s0 + i] >> 16) & 255], 1);
    __syncthreads();
    int v = h[t];
    ex[t] = v;
    __syncthreads();
    for (int o = 1; o < 256; o <<= 1) {
        int xx = (t >= o) ? ex[t - o] : 0;
        __syncthreads();
        ex[t] += xx;
        __syncthreads();
    }
    int excl = ex[t] - v;
    int n = b * 256 + t;
    if (n < NNODES) {
        rowptr[n] = s0 + excl;
        dinv[n] = rsqrtf((float)v + 1.0f);
    }
    if (b == 0 && t == 0) rowptr[NNODES] = NEDGES;
    cur[t] = excl;
    __syncthreads();
    for (int i = t; i < S; i += 256) {
        unsigned pk = buck[s0 + i];
        int dl = (pk >> 16) & 255;
        int p = atomicAdd(&cur[dl], 1);
        ssrc[s0 + p] = (int)(pk & 0xFFFFu);
    }
}

// ------ gemm0: g16 = fp16((x @ W0) * dinv[row]) --------------------------
// Direct fp32 x read + in-register split, XOR-swizzled LDS-A (proven R9).

__global__ __launch_bounds__(256) void k_gemm0(
    const float* __restrict__ x, const short* __restrict__ Bh,
    const short* __restrict__ Bl, const float* __restrict__ dinv,
    _Float16* __restrict__ g16) {
    __shared__ __align__(16) short sAh[64 * 64], sAl[64 * 64];
    __shared__ __align__(16) short sBh[128 * 64], sBl[128 * 64];
    const int t = threadIdx.x, lane = t & 63, w = t >> 6;
    const int row0 = blockIdx.x * 64;
    const int lr = lane >> 3, lz = lane & 7;
    const int swz = (lz ^ lr) * 8;
    const int fr = lane & 15, fq = lane >> 4;
    floatx4 acc[8] = {};
    const int ar = t >> 2, ac = t & 3;
    int garow = row0 + ar;
    if (garow >= NNODES) garow = NNODES - 1;
    const float* xrow = x + (size_t)garow * 256 + ac * 16;

    for (int k0 = 0; k0 < 256; k0 += 64) {
        const float4* xp = (const float4*)(xrow + k0);
        float4 f0 = xp[0], f1 = xp[1], f2 = xp[2], f3 = xp[3];
        float va[16] = {f0.x, f0.y, f0.z, f0.w, f1.x, f1.y, f1.z, f1.w,
                        f2.x, f2.y, f2.z, f2.w, f3.x, f3.y, f3.z, f3.w};
        short8 h0, h1, l0, l1;
#pragma unroll
        for (int j = 0; j < 8; j++) {
            short h, l;
            split_bf16(va[j], h, l);     h0[j] = h; l0[j] = l;
            split_bf16(va[8 + j], h, l); h1[j] = h; l1[j] = l;
        }
        int c0 = ac * 2;
        *(short8*)&sAh[ar * 64 + ((c0 ^ (ar & 7)) * 8)] = h0;
        *(short8*)&sAh[ar * 64 + (((c0 + 1) ^ (ar & 7)) * 8)] = h1;
        *(short8*)&sAl[ar * 64 + ((c0 ^ (ar & 7)) * 8)] = l0;
        *(short8*)&sAl[ar * 64 + (((c0 + 1) ^ (ar & 7)) * 8)] = l1;
#pragma unroll
        for (int jj = 0; jj < 4; jj++) {
            int j = w * 4 + jj;
            size_t go = (size_t)(j * 8 + lr) * 256 + k0 + swz;
            async16(&Bh[go], &sBh[j * 512 + lane * 8]);
            async16(&Bl[go], &sBl[j * 512 + lane * 8]);
        }
        __syncthreads();
#pragma unroll
        for (int ks = 0; ks < 2; ks++) {
            int R = w * 16 + fr;
            int ca = ((ks * 4 + fq) ^ (R & 7)) * 8;
            short8 ah = *(const short8*)&sAh[R * 64 + ca];
            short8 al = *(const short8*)&sAl[R * 64 + ca];
#pragma unroll
            for (int nt = 0; nt < 8; nt++) {
                int n = nt * 16 + fr;
                int cb = ((ks * 4 + fq) ^ (n & 7)) * 8;
                short8 bh = *(const short8*)&sBh[n * 64 + cb];
                short8 bl = *(const short8*)&sBl[n * 64 + cb];
                acc[nt] = __builtin_amdgcn_mfma_f32_16x16x32_bf16(ah, bh, acc[nt], 0, 0, 0);
                acc[nt] = __builtin_amdgcn_mfma_f32_16x16x32_bf16(ah, bl, acc[nt], 0, 0, 0);
                acc[nt] = __builtin_amdgcn_mfma_f32_16x16x32_bf16(al, bh, acc[nt], 0, 0, 0);
            }
        }
        __syncthreads();
    }
#pragma unroll
    for (int rr = 0; rr < 4; rr++) {
        int gw = row0 + w * 16 + fq * 4 + rr;
        if (gw < NNODES) {
            float dv = dinv[gw];
#pragma unroll
            for (int nt = 0; nt < 8; nt++)
                g16[(size_t)gw * 128 + nt * 16 + fr] =
                    (_Float16)(acc[nt][rr] * dv);
        }
    }
}

// ------ gemm (layers 1/2): g16 = fp16((A @ W) * dinv), proven R8 ---------

template <int BN>
__global__ __launch_bounds__(256) void k_gemm2(
    const short* __restrict__ Ah, const short* __restrict__ Al,
    const short* __restrict__ Bh, const short* __restrict__ Bl,
    const float* __restrict__ dinv, _Float16* __restrict__ g16, int K) {
    constexpr int BM = 64, BK = 64;
    constexpr int NT = BN / 16;
    __shared__ __align__(16) short sAh[BM * BK], sAl[BM * BK];
    __shared__ __align__(16) short sBh[BN * BK], sBl[BN * BK];

    const int tid = threadIdx.x, lane = tid & 63, w = tid >> 6;
    const int row0 = blockIdx.x * BM;
    const int lr = lane >> 3;
    const int lz = lane & 7;
    const int swz = (lz ^ lr) * 8;
    const int fr = lane & 15, fq = lane >> 4;

    floatx4 acc[NT] = {};

    for (int k0 = 0; k0 < K; k0 += BK) {
#pragma unroll
        for (int jj = 0; jj < 2; jj++) {
            int j = w * 2 + jj;
            int grow = row0 + j * 8 + lr;
            if (grow >= NNODES) grow = NNODES - 1;
            size_t go = (size_t)grow * K + k0 + swz;
            async16(&Ah[go], &sAh[j * 8 * BK + lane * 8]);
            async16(&Al[go], &sAl[j * 8 * BK + lane * 8]);
        }
#pragma unroll
        for (int jj = 0; jj < BN / 32; jj++) {
            int j = w * (BN / 32) + jj;
            size_t go = (size_t)(j * 8 + lr) * K + k0 + swz;
            async16(&Bh[go], &sBh[j * 8 * BK + lane * 8]);
            async16(&Bl[go], &sBl[j * 8 * BK + lane * 8]);
        }
        __syncthreads();

#pragma unroll
        for (int ks = 0; ks < 2; ks++) {
            int R = w * 16 + fr;
            int ca = ((ks * 4 + fq) ^ (R & 7)) * 8;
            short8 ah = *(const short8*)&sAh[R * BK + ca];
            short8 al = *(const short8*)&sAl[R * BK + ca];
#pragma unroll
            for (int nt = 0; nt < NT; nt++) {
                int n = nt * 16 + fr;
                int cb = ((ks * 4 + fq) ^ (n & 7)) * 8;
                short8 bh = *(const short8*)&sBh[n * BK + cb];
                short8 bl = *(const short8*)&sBl[n * BK + cb];
                acc[nt] = __builtin_amdgcn_mfma_f32_16x16x32_bf16(ah, bh, acc[nt], 0, 0, 0);
                acc[nt] = __builtin_amdgcn_mfma_f32_16x16x32_bf16(ah, bl, acc[nt], 0, 0, 0);
                acc[nt] = __builtin_amdgcn_mfma_f32_16x16x32_bf16(al, bh, acc[nt], 0, 0, 0);
            }
        }
        __syncthreads();
    }

#pragma unroll
    for (int rr = 0; rr < 4; rr++) {
        int grow = row0 + w * 16 + fq * 4 + rr;
        if (grow < NNODES) {
            float dv = dinv[grow];
#pragma unroll
            for (int nt = 0; nt < NT; nt++)
                g16[(size_t)grow * BN + nt * 16 + fr] =
                    (_Float16)(acc[nt][rr] * dv);
        }
    }
}

// ------ Aggregation with LDS edge-list broadcast (best: R13) -------------
// F8 threads per node; edge list loaded to LDS once per node, broadcast to
// all chunk-threads. Thread-per-16B-chunk row-major gathers (TA-roofline).

template <int F>
__global__ __launch_bounds__(256) void k_agg(const _Float16* __restrict__ g,
                                             const int* __restrict__ ssrc,
                                             const int* __restrict__ rowptr,
                                             const float* __restrict__ dinv,
                                             const float* __restrict__ bias,
                                             float* __restrict__ outf,
                                             short* __restrict__ oh,
                                             short* __restrict__ ol,
                                             int relu, int writebf) {
    constexpr int F8 = F / 8;          // threads per node (16 or 8)
    constexpr int NPB = 256 / F8;      // nodes per block (16 or 32)
    __shared__ int sED[NPB][64];
    int t = threadIdx.x;
    int ln = t / F8;
    int c8 = t - ln * F8;
    int n = blockIdx.x * NPB + ln;
    bool valid = (n < NNODES);
    int nc = valid ? n : NNODES - 1;

    int e0 = rowptr[nc], e1 = rowptr[nc + 1];
    int deg = e1 - e0;
    int cnt = deg < 64 ? deg : 64;
    for (int i = c8; i < cnt; i += F8) sED[ln][i] = ssrc[e0 + i];
    __syncthreads();

    const f16x8* gp = (const f16x8*)g;
    f16x8 sv = gp[(size_t)nc * F8 + c8];       // self term
    float a0[8], a1[8], a2[8], a3[8];
#pragma unroll
    for (int j = 0; j < 8; j++) {
        a0[j] = (float)sv[j];
        a1[j] = 0.f; a2[j] = 0.f; a3[j] = 0.f;
    }
    int i = 0;
    for (; i + 4 <= cnt; i += 4) {
        int s0 = sED[ln][i], s1 = sED[ln][i + 1];
        int s2 = sED[ln][i + 2], s3 = sED[ln][i + 3];
        f16x8 v0 = gp[(size_t)s0 * F8 + c8];
        f16x8 v1 = gp[(size_t)s1 * F8 + c8];
        f16x8 v2 = gp[(size_t)s2 * F8 + c8];
        f16x8 v3 = gp[(size_t)s3 * F8 + c8];
#pragma unroll
        for (int j = 0; j < 8; j++) {
            a0[j] += (float)v0[j];
            a1[j] += (float)v1[j];
            a2[j] += (float)v2[j];
            a3[j] += (float)v3[j];
        }
    }
    for (; i < cnt; i++) {
        int s = sED[ln][i];
        f16x8 v = gp[(size_t)s * F8 + c8];
#pragma unroll
        for (int j = 0; j < 8; j++) a0[j] += (float)v[j];
    }
    // rare overflow (deg > 64): direct from global
    for (int e = e0 + 64; e < e1; e++) {
        int s = ssrc[e];
        f16x8 v = gp[(size_t)s * F8 + c8];
#pragma unroll
        for (int j = 0; j < 8; j++) a0[j] += (float)v[j];
    }

    float dv = dinv[nc];
    float o[8];
#pragma unroll
    for (int j = 0; j < 8; j++) {
        float s = (a0[j] + a1[j]) + (a2[j] + a3[j]);
        o[j] = s * dv + bias[c8 * 8 + j];
        if (relu) o[j] = fmaxf(o[j], 0.f);
    }
    if (!valid) return;
    if (writebf) {
        short8 h8, l8;
#pragma unroll
        for (int j = 0; j < 8; j++) {
            short h, l;
            split_bf16(o[j], h, l);
            h8[j] = h; l8[j] = l;
        }
        *(short8*)&oh[(size_t)n * F + c8 * 8] = h8;
        *(short8*)&ol[(size_t)n * F + c8 * 8] = l8;
    } else {
        *(float4*)&outf[(size_t)n * F + c8 * 8] =
            make_float4(o[0], o[1], o[2], o[3]);
        *(float4*)&outf[(size_t)n * F + c8 * 8 + 4] =
            make_float4(o[4], o[5], o[6], o[7]);
    }
}

// ---------------- launch ----------------

static inline size_t align256(size_t x) { return (x + 255) & ~(size_t)255; }

extern "C" void kernel_launch(void* const* d_in, const int* in_sizes, int n_in,
                              void* d_out, int out_size, void* d_ws, size_t ws_size,
                              hipStream_t stream) {
    const float* x  = (const float*)d_in[0];
    const int*   ei = (const int*)d_in[1];
    const float* W0 = (const float*)d_in[2];
    const float* b0 = (const float*)d_in[3];
    const float* W1 = (const float*)d_in[4];
    const float* b1 = (const float*)d_in[5];
    const float* W2 = (const float*)d_in[6];
    const float* b2 = (const float*)d_in[7];
    float* out = (float*)d_out;

    const int* src = ei;
    const int* dst = ei + NEDGES;

    char* w = (char*)d_ws;
    size_t off = 0;
    float* dinv    = (float*)(w + off); off = align256(off + NNODES * 4);
    int* rowptr    = (int*)(w + off);   off = align256(off + (NNODES + 1) * 4);
    int* hist2d    = (int*)(w + off);   off = align256(off + 256 * 256 * 4);
    unsigned* buck = (unsigned*)(w + off); off = align256(off + (size_t)NEDGES * 4);
    int* ssrc      = (int*)(w + off);   off = align256(off + (size_t)NEDGES * 4);
    short* W0h     = (short*)(w + off); off = align256(off + 256 * 128 * 2);
    short* W0l     = (short*)(w + off); off = align256(off + 256 * 128 * 2);
    short* W1h     = (short*)(w + off); off = align256(off + 128 * 128 * 2);
    short* W1l     = (short*)(w + off); off = align256(off + 128 * 128 * 2);
    short* W2h     = (short*)(w + off); off = align256(off + 128 * 64 * 2);
    short* W2l     = (short*)(w + off); off = align256(off + 128 * 64 * 2);
    short* ph      = (short*)(w + off); off = align256(off + (size_t)NNODES * 128 * 2);
    short* pl      = (short*)(w + off); off = align256(off + (size_t)NNODES * 128 * 2);
    _Float16* g16  = (_Float16*)(w + off); off = align256(off + (size_t)NNODES * 128 * 2);

    const int MB = (NNODES + 63) / 64;            // 782
    const int AB128 = (NNODES + 15) / 16;         // 3125 (16 nodes/block)
    const int AB64  = (NNODES + 31) / 32;         // 1563 (32 nodes/block)

    // 1) prep: weights + coarse histogram
    k_prep<<<PREP_TOT, 256, 0, stream>>>(W0, W0h, W0l, W1, W1h, W1l,
                                         W2, W2h, W2l, dst, hist2d);
    // 2) coarse scatter
    k_p2<<<256, 256, 0, stream>>>(src, dst, hist2d, buck);
    // 3) finalize: rowptr/dinv/ssrc
    k_p3<<<256, 256, 0, stream>>>(buck, hist2d, rowptr, dinv, ssrc);

    // layer 0 (direct x)
    k_gemm0<<<MB, 256, 0, stream>>>(x, W0h, W0l, dinv, g16);
    k_agg<128><<<AB128, 256, 0, stream>>>(g16, ssrc, rowptr, dinv, b0,
                                          (float*)nullptr, ph, pl, 1, 1);
    // layer 1
    k_gemm2<128><<<MB, 256, 0, stream>>>(ph, pl, W1h, W1l, dinv, g16, 128);
    k_agg<128><<<AB128, 256, 0, stream>>>(g16, ssrc, rowptr, dinv, b1,
                                          (float*)nullptr, ph, pl, 1, 1);
    // layer 2
    k_gemm2<64><<<MB, 256, 0, stream>>>(ph, pl, W2h, W2l, dinv, g16, 128);
    k_agg<64><<<AB64, 256, 0, stream>>>(g16, ssrc, rowptr, dinv, b2,
                                        out, (short*)nullptr, (short*)nullptr, 0, 0);
    (void)in_sizes; (void)n_in; (void)out_size; (void)ws_size;
}